// Round 2
// baseline (3514.292 us; speedup 1.0000x reference)
//
#include <hip/hip_runtime.h>

#define DIMV 768
#define BATCH 16
#define SEQ 1024
#define LN_EPS 1e-5f

// ---------------------------------------------------------------------------
// Generic NT GEMM: C[m,n] = scale * sum_k A[m,k]*B[n,k] (+ bias[n])
// Tiles 64x64, TK=16, block 16x16 threads, 4x4 microtile per thread.
// Batched via blockIdx.z with element strides sAz/sBz/sCz.
// ---------------------------------------------------------------------------
__global__ __launch_bounds__(256) void gemm_nt(
    const float* __restrict__ A, const float* __restrict__ B,
    const float* __restrict__ bias, float* __restrict__ C,
    int K, int lda, int ldb, int ldc, float scale,
    long long sAz, long long sBz, long long sCz)
{
    A += (long long)blockIdx.z * sAz;
    B += (long long)blockIdx.z * sBz;
    C += (long long)blockIdx.z * sCz;

    __shared__ float As[16][64];   // [k][m]
    __shared__ float Bs[16][64];   // [k][n]

    const int tx = threadIdx.x, ty = threadIdx.y;
    const int t  = ty * 16 + tx;
    const int lr = t >> 2;          // 0..63: row within tile
    const int lc = (t & 3) << 2;    // 0,4,8,12: k offset
    const long long rowA = blockIdx.y * 64 + lr;
    const long long rowB = blockIdx.x * 64 + lr;

    float acc[4][4] = {};

    for (int k0 = 0; k0 < K; k0 += 16) {
        float4 a = *reinterpret_cast<const float4*>(&A[rowA * lda + k0 + lc]);
        float4 b = *reinterpret_cast<const float4*>(&B[rowB * ldb + k0 + lc]);
        __syncthreads();            // previous iter's reads done
        As[lc + 0][lr] = a.x; As[lc + 1][lr] = a.y;
        As[lc + 2][lr] = a.z; As[lc + 3][lr] = a.w;
        Bs[lc + 0][lr] = b.x; Bs[lc + 1][lr] = b.y;
        Bs[lc + 2][lr] = b.z; Bs[lc + 3][lr] = b.w;
        __syncthreads();
        #pragma unroll
        for (int kk = 0; kk < 16; ++kk) {
            float4 av = *reinterpret_cast<const float4*>(&As[kk][ty * 4]);
            float4 bv = *reinterpret_cast<const float4*>(&Bs[kk][tx * 4]);
            float aa[4] = {av.x, av.y, av.z, av.w};
            float bb[4] = {bv.x, bv.y, bv.z, bv.w};
            #pragma unroll
            for (int i = 0; i < 4; ++i)
                #pragma unroll
                for (int j = 0; j < 4; ++j)
                    acc[i][j] += aa[i] * bb[j];
        }
    }

    #pragma unroll
    for (int i = 0; i < 4; ++i) {
        long long row = blockIdx.y * 64 + ty * 4 + i;
        #pragma unroll
        for (int j = 0; j < 4; ++j) {
            int col = blockIdx.x * 64 + tx * 4 + j;
            float v = acc[i][j] * scale;
            if (bias) v += bias[col];
            C[row * ldc + col] = v;
        }
    }
}

// ---------------------------------------------------------------------------
// NN GEMM (for P @ V): C[m,n] (+)= sum_k P[m,k]*V[k,n]
// ---------------------------------------------------------------------------
__global__ __launch_bounds__(256) void gemm_nn_acc(
    const float* __restrict__ P, const float* __restrict__ V,
    float* __restrict__ C, int K, int ldp, int ldv, int ldc, int accumulate,
    long long sPz, long long sVz, long long sCz)
{
    P += (long long)blockIdx.z * sPz;
    V += (long long)blockIdx.z * sVz;
    C += (long long)blockIdx.z * sCz;

    __shared__ float Ps[16][64];   // [k][m]
    __shared__ float Vs[16][64];   // [k][n]

    const int tx = threadIdx.x, ty = threadIdx.y;
    const int t  = ty * 16 + tx;
    const int lr = t >> 2;          // P-staging row 0..63
    const int lc = (t & 3) << 2;    // P-staging k offset
    const int vk = t >> 4;          // V-staging k row 0..15
    const int vn = (t & 15) << 2;   // V-staging n offset
    const long long rowP = blockIdx.y * 64 + lr;
    const int colV = blockIdx.x * 64 + vn;

    float acc[4][4] = {};

    for (int k0 = 0; k0 < K; k0 += 16) {
        float4 a = *reinterpret_cast<const float4*>(&P[rowP * ldp + k0 + lc]);
        float4 b = *reinterpret_cast<const float4*>(&V[(long long)(k0 + vk) * ldv + colV]);
        __syncthreads();
        Ps[lc + 0][lr] = a.x; Ps[lc + 1][lr] = a.y;
        Ps[lc + 2][lr] = a.z; Ps[lc + 3][lr] = a.w;
        *reinterpret_cast<float4*>(&Vs[vk][vn]) = b;
        __syncthreads();
        #pragma unroll
        for (int kk = 0; kk < 16; ++kk) {
            float4 av = *reinterpret_cast<const float4*>(&Ps[kk][ty * 4]);
            float4 bv = *reinterpret_cast<const float4*>(&Vs[kk][tx * 4]);
            float aa[4] = {av.x, av.y, av.z, av.w};
            float bb[4] = {bv.x, bv.y, bv.z, bv.w};
            #pragma unroll
            for (int i = 0; i < 4; ++i)
                #pragma unroll
                for (int j = 0; j < 4; ++j)
                    acc[i][j] += aa[i] * bb[j];
        }
    }

    #pragma unroll
    for (int i = 0; i < 4; ++i) {
        long long row = blockIdx.y * 64 + ty * 4 + i;
        #pragma unroll
        for (int j = 0; j < 4; ++j) {
            int col = blockIdx.x * 64 + tx * 4 + j;
            long long idx = row * ldc + col;
            if (accumulate) C[idx] += acc[i][j];
            else            C[idx]  = acc[i][j];
        }
    }
}

// ---------------------------------------------------------------------------
// Row softmax over 1024 columns. One 256-thread block per row.
// ---------------------------------------------------------------------------
__global__ __launch_bounds__(256) void softmax_rows(float* __restrict__ P)
{
    float* p = P + (long long)blockIdx.x * SEQ;
    const int t = threadIdx.x;
    __shared__ float red[256];

    float4 v = *reinterpret_cast<const float4*>(&p[t * 4]);
    float mx = fmaxf(fmaxf(v.x, v.y), fmaxf(v.z, v.w));
    red[t] = mx;
    __syncthreads();
    for (int s = 128; s > 0; s >>= 1) {
        if (t < s) red[t] = fmaxf(red[t], red[t + s]);
        __syncthreads();
    }
    mx = red[0];
    __syncthreads();

    v.x = __expf(v.x - mx); v.y = __expf(v.y - mx);
    v.z = __expf(v.z - mx); v.w = __expf(v.w - mx);
    float sum = v.x + v.y + v.z + v.w;
    red[t] = sum;
    __syncthreads();
    for (int s = 128; s > 0; s >>= 1) {
        if (t < s) red[t] += red[t + s];
        __syncthreads();
    }
    float inv = 1.0f / red[0];

    v.x *= inv; v.y *= inv; v.z *= inv; v.w *= inv;
    *reinterpret_cast<float4*>(&p[t * 4]) = v;
}

// ---------------------------------------------------------------------------
// h = LayerNorm(ACC + x_C) * gamma + beta. One 256-thread block per row (768).
// ---------------------------------------------------------------------------
__global__ __launch_bounds__(256) void add_layernorm(
    const float* __restrict__ ACC, const float* __restrict__ xC,
    const float* __restrict__ gamma, const float* __restrict__ beta,
    float* __restrict__ H)
{
    const long long row = blockIdx.x;
    const float* a = ACC + row * DIMV;
    const float* x = xC  + row * DIMV;
    float*       h = H   + row * DIMV;
    const int t = threadIdx.x;

    __shared__ float r1[256];
    __shared__ float r2[256];

    float vals[3];
    float s = 0.f, ss = 0.f;
    #pragma unroll
    for (int i = 0; i < 3; ++i) {
        float v = a[t + i * 256] + x[t + i * 256];
        vals[i] = v;
        s += v; ss += v * v;
    }
    r1[t] = s; r2[t] = ss;
    __syncthreads();
    for (int st = 128; st > 0; st >>= 1) {
        if (t < st) { r1[t] += r1[t + st]; r2[t] += r2[t + st]; }
        __syncthreads();
    }
    const float mu  = r1[0] * (1.0f / DIMV);
    const float var = r2[0] * (1.0f / DIMV) - mu * mu;
    const float inv = rsqrtf(var + LN_EPS);

    #pragma unroll
    for (int i = 0; i < 3; ++i) {
        int j = t + i * 256;
        h[j] = (vals[i] - mu) * inv * gamma[j] + beta[j];
    }
}

// ---------------------------------------------------------------------------
// Launch — chunked over batches so workspace footprint adapts to ws_size.
// Per-batch footprint: 6 * (1024*768) + 1024*1024 floats = 23.07 MB.
// ---------------------------------------------------------------------------
extern "C" void kernel_launch(void* const* d_in, const int* in_sizes, int n_in,
                              void* d_out, int out_size, void* d_ws, size_t ws_size,
                              hipStream_t stream)
{
    const float* xA    = (const float*)d_in[0];
    const float* xB    = (const float*)d_in[1];
    const float* xC    = (const float*)d_in[2];
    const float* Wq    = (const float*)d_in[3];
    const float* bq    = (const float*)d_in[4];
    const float* Wk    = (const float*)d_in[5];
    const float* bk    = (const float*)d_in[6];
    const float* Wv    = (const float*)d_in[7];
    const float* bv    = (const float*)d_in[8];
    const float* gamma = (const float*)d_in[9];
    const float* beta  = (const float*)d_in[10];
    const float* Wfc   = (const float*)d_in[11];
    const float* bfc   = (const float*)d_in[12];
    float* out = (float*)d_out;

    const long long perB  = (long long)SEQ * DIMV;        // 786,432 elems
    const long long perP  = (long long)SEQ * SEQ;          // 1,048,576 elems
    const long long perBatchFloats = 6 * perB + perP;      // 5,767,168
    const long long perBatchBytes  = perBatchFloats * 4;   // ~23.07 MB

    long long C = (long long)(ws_size / (size_t)perBatchBytes);
    if (C > BATCH) C = BATCH;
    if (C < 1)     C = 1;   // nothing smaller is possible; best effort

    const float scale = 0.03608439182435161f;  // 1/sqrt(768)
    dim3 blk(16, 16);

    for (int b0 = 0; b0 < BATCH; b0 += (int)C) {
        const int Cb = (int)((b0 + C <= BATCH) ? C : (BATCH - b0));
        const long long off = (long long)b0 * perB;

        // chunk workspace layout
        float* ws  = (float*)d_ws;
        float* Q   = ws;                    // reused as H after attention
        float* KA  = ws + 1 * Cb * perB;
        float* KB  = ws + 2 * Cb * perB;
        float* VA  = ws + 3 * Cb * perB;
        float* VB  = ws + 4 * Cb * perB;
        float* ACC = ws + 5 * Cb * perB;
        float* P   = ws + 6 * Cb * perB;    // Cb * 1024 * 1024

        dim3 gproj(DIMV / 64, (Cb * SEQ) / 64, 1);
        dim3 gsc(SEQ / 64, SEQ / 64, Cb);
        dim3 gpv(DIMV / 64, SEQ / 64, Cb);

        // 1) projections (rows = Cb*1024 flattened)
        gemm_nt<<<gproj, blk, 0, stream>>>(xC + off, Wq, bq, Q,  DIMV, DIMV, DIMV, DIMV, 1.f, 0, 0, 0);
        gemm_nt<<<gproj, blk, 0, stream>>>(xA + off, Wk, bk, KA, DIMV, DIMV, DIMV, DIMV, 1.f, 0, 0, 0);
        gemm_nt<<<gproj, blk, 0, stream>>>(xB + off, Wk, bk, KB, DIMV, DIMV, DIMV, DIMV, 1.f, 0, 0, 0);
        gemm_nt<<<gproj, blk, 0, stream>>>(xA + off, Wv, bv, VA, DIMV, DIMV, DIMV, DIMV, 1.f, 0, 0, 0);
        gemm_nt<<<gproj, blk, 0, stream>>>(xB + off, Wv, bv, VB, DIMV, DIMV, DIMV, DIMV, 1.f, 0, 0, 0);

        // 2) branch A: scores -> softmax -> PV (overwrite ACC)
        gemm_nt<<<gsc, blk, 0, stream>>>(Q, KA, nullptr, P, DIMV, DIMV, DIMV, SEQ, scale, perB, perB, perP);
        softmax_rows<<<Cb * SEQ, 256, 0, stream>>>(P);
        gemm_nn_acc<<<gpv, blk, 0, stream>>>(P, VA, ACC, SEQ, SEQ, DIMV, DIMV, 0, perP, perB, perB);

        // 3) branch B: scores -> softmax -> PV (accumulate into ACC)
        gemm_nt<<<gsc, blk, 0, stream>>>(Q, KB, nullptr, P, DIMV, DIMV, DIMV, SEQ, scale, perB, perB, perP);
        softmax_rows<<<Cb * SEQ, 256, 0, stream>>>(P);
        gemm_nn_acc<<<gpv, blk, 0, stream>>>(P, VB, ACC, SEQ, SEQ, DIMV, DIMV, 1, perP, perB, perB);

        // 4) h = LN(ACC + xC); write into Q buffer (Q no longer needed)
        add_layernorm<<<Cb * SEQ, 256, 0, stream>>>(ACC, xC + off, gamma, beta, Q);

        // 5) out = h @ Wfc^T + bfc
        gemm_nt<<<gproj, blk, 0, stream>>>(Q, Wfc, bfc, out + off, DIMV, DIMV, DIMV, DIMV, 1.f, 0, 0, 0);
    }
}

// Round 4
// 1071.902 us; speedup vs baseline: 3.2786x; 3.2786x over previous
//
#include <hip/hip_runtime.h>

#define DIMV 768
#define BATCH 16
#define SEQ 1024
#define LN_EPS 1e-5f

typedef __attribute__((ext_vector_type(8))) short bf16x8;   // 8 bf16 = 4 VGPRs
typedef __attribute__((ext_vector_type(4))) float f32x4;
typedef unsigned short ushort_t;

__device__ __forceinline__ unsigned short f2bf(float f) {
    unsigned u = __float_as_uint(f);
    u = (u + 0x7FFFu + ((u >> 16) & 1u)) >> 16;
    return (unsigned short)u;
}

// ---------------------------------------------------------------------------
// bf16 MFMA NT GEMM (m97 structure): C[m,n] = scale*sum_k A[m,k]*B[n,k] + bias[n]
// A: bf16 row-major [M, lda]; B: bf16 row-major [N, ldb] (i.e. B^T input).
// 128x128 tile, BK=32, 256 threads = 4 waves in 2x2 grid, 4x4 MFMA tiles/wave.
// mode: 0 = f32 out; 1 = bf16 out; 2 = bf16 out transposed per-(local)batch
//       (dst[b][n][s], b = m>>10, s = m&1023); 3 = f32 accumulate (C += val).
// ---------------------------------------------------------------------------
__global__ __launch_bounds__(256) void gemm_bf16_nt(
    const ushort_t* __restrict__ A, const ushort_t* __restrict__ B,
    const float* __restrict__ bias, void* __restrict__ Cout,
    int K, int lda, int ldb, int ldc, float scale, int mode,
    long long sAz, long long sBz, long long sCz)
{
    A += (long long)blockIdx.z * sAz;
    B += (long long)blockIdx.z * sBz;
    float*    Cf = (float*)Cout    + ((mode == 0 || mode == 3) ? (long long)blockIdx.z * sCz : 0);
    ushort_t* Ch = (ushort_t*)Cout + ((mode == 1 || mode == 2) ? (long long)blockIdx.z * sCz : 0);

    __shared__ ushort_t As[128 * 32];   // 8 KB, row-major [128][32], no padding
    __shared__ ushort_t Bs[128 * 32];   // (global_load_lds: lane-ordered contiguous)

    const int t    = threadIdx.x;       // 0..255
    const int wave = t >> 6;
    const int lane = t & 63;
    const int quad = lane >> 4;         // 0..3
    const int lr   = lane & 15;         // 0..15
    const int wy   = wave >> 1;         // 0/1: m-half
    const int wx   = wave & 1;          // 0/1: n-half

    const int m0 = blockIdx.y * 128;
    const int n0 = blockIdx.x * 128;

    f32x4 acc[4][4] = {};

    for (int k0 = 0; k0 < K; k0 += 32) {
        __syncthreads();   // previous iteration's LDS reads complete
        #pragma unroll
        for (int i = 0; i < 2; ++i) {
            const int idx = t + 256 * i;          // 0..511 covers 128 rows x 4 chunks
            const int r   = idx >> 2;             // row in tile
            const int c   = (idx & 3) * 8;        // bf16 col offset (16B chunks)
            const ushort_t* ga = A + (long long)(m0 + r) * lda + k0 + c;
            const ushort_t* gb = B + (long long)(n0 + r) * ldb + k0 + c;
            __builtin_amdgcn_global_load_lds(
                (const __attribute__((address_space(1))) unsigned int*)ga,
                (__attribute__((address_space(3))) unsigned int*)&As[idx * 8], 16, 0, 0);
            __builtin_amdgcn_global_load_lds(
                (const __attribute__((address_space(1))) unsigned int*)gb,
                (__attribute__((address_space(3))) unsigned int*)&Bs[idx * 8], 16, 0, 0);
        }
        __syncthreads();   // compiler emits s_waitcnt vmcnt(0) before s_barrier

        bf16x8 af[4], bfr[4];
        #pragma unroll
        for (int i = 0; i < 4; ++i) {
            const int row = wy * 64 + i * 16 + lr;      // A[m][k], m = lane&15
            af[i] = *(const bf16x8*)&As[row * 32 + quad * 8];
        }
        #pragma unroll
        for (int j = 0; j < 4; ++j) {
            const int row = wx * 64 + j * 16 + lr;      // B^T[n][k], n = lane&15
            bfr[j] = *(const bf16x8*)&Bs[row * 32 + quad * 8];
        }
        #pragma unroll
        for (int i = 0; i < 4; ++i)
            #pragma unroll
            for (int j = 0; j < 4; ++j)
                acc[i][j] = __builtin_amdgcn_mfma_f32_16x16x32_bf16(
                    af[i], bfr[j], acc[i][j], 0, 0, 0);
    }

    // epilogue: D row(m) = quad*4 + reg, col(n) = lane&15  [m89-verified mapping]
    #pragma unroll
    for (int j = 0; j < 4; ++j) {
        const int n = n0 + wx * 64 + j * 16 + lr;
        const float bv = bias ? bias[n] : 0.0f;
        #pragma unroll
        for (int i = 0; i < 4; ++i) {
            #pragma unroll
            for (int r = 0; r < 4; ++r) {
                const int m = m0 + wy * 64 + i * 16 + quad * 4 + r;
                const float val = acc[i][j][r] * scale + bv;
                if (mode == 0) {
                    Cf[(long long)m * ldc + n] = val;
                } else if (mode == 3) {
                    Cf[(long long)m * ldc + n] += val;
                } else if (mode == 1) {
                    Ch[(long long)m * ldc + n] = f2bf(val);
                } else {
                    const int b = m >> 10, s = m & 1023;
                    Ch[(long long)b * (DIMV * SEQ) + (long long)n * SEQ + s] = f2bf(val);
                }
            }
        }
    }
}

// ---------------------------------------------------------------------------
// f32 -> bf16 conversion, 4 elems/thread, count divisible by 1024
// ---------------------------------------------------------------------------
__global__ __launch_bounds__(256) void f32_to_bf16(
    const float* __restrict__ in, ushort_t* __restrict__ out)
{
    const long long i = ((long long)blockIdx.x * 256 + threadIdx.x) * 4;
    float4 v = *reinterpret_cast<const float4*>(in + i);
    ushort4 o;
    o.x = f2bf(v.x); o.y = f2bf(v.y); o.z = f2bf(v.z); o.w = f2bf(v.w);
    *reinterpret_cast<ushort4*>(out + i) = o;
}

// ---------------------------------------------------------------------------
// Row softmax over 1024 f32 logits -> bf16 probs. One 256-thread block/row.
// ---------------------------------------------------------------------------
__global__ __launch_bounds__(256) void softmax_rows(
    const float* __restrict__ S, ushort_t* __restrict__ P)
{
    const float* s = S + (long long)blockIdx.x * SEQ;
    ushort_t*    p = P + (long long)blockIdx.x * SEQ;
    const int t = threadIdx.x;
    __shared__ float red[256];

    float4 v = *reinterpret_cast<const float4*>(&s[t * 4]);
    float mx = fmaxf(fmaxf(v.x, v.y), fmaxf(v.z, v.w));
    red[t] = mx;
    __syncthreads();
    for (int st = 128; st > 0; st >>= 1) {
        if (t < st) red[t] = fmaxf(red[t], red[t + st]);
        __syncthreads();
    }
    mx = red[0];
    __syncthreads();

    v.x = __expf(v.x - mx); v.y = __expf(v.y - mx);
    v.z = __expf(v.z - mx); v.w = __expf(v.w - mx);
    red[t] = v.x + v.y + v.z + v.w;
    __syncthreads();
    for (int st = 128; st > 0; st >>= 1) {
        if (t < st) red[t] += red[t + st];
        __syncthreads();
    }
    const float inv = 1.0f / red[0];

    ushort4 o;
    o.x = f2bf(v.x * inv); o.y = f2bf(v.y * inv);
    o.z = f2bf(v.z * inv); o.w = f2bf(v.w * inv);
    *reinterpret_cast<ushort4*>(&p[t * 4]) = o;
}

// ---------------------------------------------------------------------------
// h = LayerNorm(ACC + xC) * gamma + beta -> bf16. One block per row (768).
// ---------------------------------------------------------------------------
__global__ __launch_bounds__(256) void add_layernorm(
    const float* __restrict__ ACC, const float* __restrict__ xC,
    const float* __restrict__ gamma, const float* __restrict__ beta,
    ushort_t* __restrict__ H)
{
    const long long row = blockIdx.x;
    const float* a = ACC + row * DIMV;
    const float* x = xC  + row * DIMV;
    ushort_t*    h = H   + row * DIMV;
    const int t = threadIdx.x;

    __shared__ float r1[256];
    __shared__ float r2[256];

    float vals[3];
    float s = 0.f, ss = 0.f;
    #pragma unroll
    for (int i = 0; i < 3; ++i) {
        const int j = t + i * 256;
        float v = a[j] + x[j];
        vals[i] = v;
        s += v; ss += v * v;
    }
    r1[t] = s; r2[t] = ss;
    __syncthreads();
    for (int st = 128; st > 0; st >>= 1) {
        if (t < st) { r1[t] += r1[t + st]; r2[t] += r2[t + st]; }
        __syncthreads();
    }
    const float mu  = r1[0] * (1.0f / DIMV);
    const float var = r2[0] * (1.0f / DIMV) - mu * mu;
    const float inv = rsqrtf(var + LN_EPS);

    #pragma unroll
    for (int i = 0; i < 3; ++i) {
        const int j = t + i * 256;
        h[j] = f2bf((vals[i] - mu) * inv * gamma[j] + beta[j]);
    }
}

// ---------------------------------------------------------------------------
// Launch — chunked over batches; footprint adapts to ws_size.
// Persistent: 4 bf16 weight buffers (4.72 MB).
// Per-batch: 6*(S*D)*2 + (S*D)*4 + (S*S)*4 + (S*S)*2 = 18.87 MB.
// ---------------------------------------------------------------------------
extern "C" void kernel_launch(void* const* d_in, const int* in_sizes, int n_in,
                              void* d_out, int out_size, void* d_ws, size_t ws_size,
                              hipStream_t stream)
{
    const float* xA    = (const float*)d_in[0];
    const float* xB    = (const float*)d_in[1];
    const float* xC    = (const float*)d_in[2];
    const float* Wq    = (const float*)d_in[3];
    const float* bq    = (const float*)d_in[4];
    const float* Wk    = (const float*)d_in[5];
    const float* bk    = (const float*)d_in[6];
    const float* Wv    = (const float*)d_in[7];
    const float* bv    = (const float*)d_in[8];
    const float* gamma = (const float*)d_in[9];
    const float* beta  = (const float*)d_in[10];
    const float* Wfc   = (const float*)d_in[11];
    const float* bfc   = (const float*)d_in[12];
    float* out = (float*)d_out;

    const long long eW   = (long long)DIMV * DIMV;   // 589,824
    const long long perB = (long long)SEQ * DIMV;    // 786,432
    const long long perP = (long long)SEQ * SEQ;     // 1,048,576

    const long long wBytes        = 4 * eW * 2;                        // 4.72 MB
    const long long perBatchBytes = perB * (6 * 2 + 4) + perP * (4 + 2); // 18,874,368

    long long Cmax = ((long long)ws_size - wBytes) / perBatchBytes;
    if (Cmax > BATCH) Cmax = BATCH;
    if (Cmax < 1)     Cmax = 1;   // best effort (needs ~23.6 MB minimum)

    // persistent weight region
    char* cur = (char*)d_ws;
    ushort_t* Wqb  = (ushort_t*)cur; cur += eW * 2;
    ushort_t* Wkb  = (ushort_t*)cur; cur += eW * 2;
    ushort_t* Wvb  = (ushort_t*)cur; cur += eW * 2;
    ushort_t* Wfcb = (ushort_t*)cur; cur += eW * 2;
    char* chunkBase = cur;

    const float scale = 0.03608439182435161f;  // 1/sqrt(768)

    // 0) convert weights to bf16 (once)
    f32_to_bf16<<<(int)(eW / 1024), 256, 0, stream>>>(Wq,  Wqb);
    f32_to_bf16<<<(int)(eW / 1024), 256, 0, stream>>>(Wk,  Wkb);
    f32_to_bf16<<<(int)(eW / 1024), 256, 0, stream>>>(Wv,  Wvb);
    f32_to_bf16<<<(int)(eW / 1024), 256, 0, stream>>>(Wfc, Wfcb);

    for (int b0 = 0; b0 < BATCH; b0 += (int)Cmax) {
        const int Cb = (int)((b0 + Cmax <= BATCH) ? Cmax : (BATCH - b0));
        const long long off = (long long)b0 * perB;
        const int Mrows = Cb * SEQ;

        // chunk workspace layout
        char* p = chunkBase;
        ushort_t* xb  = (ushort_t*)p; p += (long long)Cb * perB * 2;  // input conv
        ushort_t* Qb  = (ushort_t*)p; p += (long long)Cb * perB * 2;  // Q, later h
        ushort_t* KAb = (ushort_t*)p; p += (long long)Cb * perB * 2;
        ushort_t* KBb = (ushort_t*)p; p += (long long)Cb * perB * 2;
        ushort_t* VtA = (ushort_t*)p; p += (long long)Cb * perB * 2;  // [b][768][1024]
        ushort_t* VtB = (ushort_t*)p; p += (long long)Cb * perB * 2;
        float*    ACC = (float*)p;    p += (long long)Cb * perB * 4;
        float*    Sf  = (float*)p;    p += (long long)Cb * perP * 4;
        ushort_t* Pb  = (ushort_t*)p; p += (long long)Cb * perP * 2;

        dim3 gproj(DIMV / 128, Mrows / 128, 1);
        dim3 gsc(SEQ / 128, SEQ / 128, Cb);
        dim3 gpv(DIMV / 128, SEQ / 128, Cb);
        const int gcv = (int)((long long)Cb * perB / 1024);

        // 1) projections (shared conversion buffer, stream-serialized)
        f32_to_bf16<<<gcv, 256, 0, stream>>>(xC + off, xb);
        gemm_bf16_nt<<<gproj, 256, 0, stream>>>(xb, Wqb, bq, Qb,  DIMV, DIMV, DIMV, DIMV, 1.f, 1, 0, 0, 0);
        f32_to_bf16<<<gcv, 256, 0, stream>>>(xA + off, xb);
        gemm_bf16_nt<<<gproj, 256, 0, stream>>>(xb, Wkb, bk, KAb, DIMV, DIMV, DIMV, DIMV, 1.f, 1, 0, 0, 0);
        gemm_bf16_nt<<<gproj, 256, 0, stream>>>(xb, Wvb, bv, VtA, DIMV, DIMV, DIMV, DIMV, 1.f, 2, 0, 0, 0);
        f32_to_bf16<<<gcv, 256, 0, stream>>>(xB + off, xb);
        gemm_bf16_nt<<<gproj, 256, 0, stream>>>(xb, Wkb, bk, KBb, DIMV, DIMV, DIMV, DIMV, 1.f, 1, 0, 0, 0);
        gemm_bf16_nt<<<gproj, 256, 0, stream>>>(xb, Wvb, bv, VtB, DIMV, DIMV, DIMV, DIMV, 1.f, 2, 0, 0, 0);

        // 2) branch A: scores -> softmax -> PV (write ACC)
        gemm_bf16_nt<<<gsc, 256, 0, stream>>>(Qb, KAb, nullptr, Sf,
            DIMV, DIMV, DIMV, SEQ, scale, 0, perB, perB, perP);
        softmax_rows<<<Cb * SEQ, 256, 0, stream>>>(Sf, Pb);
        gemm_bf16_nt<<<gpv, 256, 0, stream>>>(Pb, VtA, nullptr, ACC,
            SEQ, SEQ, SEQ, DIMV, 1.f, 0, perP, perB, perB);

        // 3) branch B: scores -> softmax -> PV (accumulate into ACC)
        gemm_bf16_nt<<<gsc, 256, 0, stream>>>(Qb, KBb, nullptr, Sf,
            DIMV, DIMV, DIMV, SEQ, scale, 0, perB, perB, perP);
        softmax_rows<<<Cb * SEQ, 256, 0, stream>>>(Sf, Pb);
        gemm_bf16_nt<<<gpv, 256, 0, stream>>>(Pb, VtB, nullptr, ACC,
            SEQ, SEQ, SEQ, DIMV, 1.f, 3, perP, perB, perB);

        // 4) h = LN(ACC + xC) -> bf16, into Qb (Q is dead now)
        add_layernorm<<<Cb * SEQ, 256, 0, stream>>>(ACC, xC + off, gamma, beta, Qb);

        // 5) out = h @ Wfc^T + bfc (f32 out)
        gemm_bf16_nt<<<gproj, 256, 0, stream>>>(Qb, Wfcb, bfc, out + off,
            DIMV, DIMV, DIMV, DIMV, 1.f, 0, 0, 0, 0);
    }
}

// Round 5
// 954.748 us; speedup vs baseline: 3.6809x; 1.1227x over previous
//
#include <hip/hip_runtime.h>

#define DIMV 768
#define BATCH 16
#define SEQ 1024
#define LN_EPS 1e-5f

typedef __attribute__((ext_vector_type(8))) short bf16x8;   // 8 bf16 = 4 VGPRs
typedef __attribute__((ext_vector_type(4))) float f32x4;
typedef unsigned short ushort_t;

__device__ __forceinline__ unsigned short f2bf(float f) {
    unsigned u = __float_as_uint(f);
    u = (u + 0x7FFFu + ((u >> 16) & 1u)) >> 16;
    return (unsigned short)u;
}

// ---------------------------------------------------------------------------
// bf16 MFMA NT GEMM, ring-3 LDS pipeline: C[m,n] = scale*sum_k A[m,k]*B[n,k]+bias
// A: bf16 row-major [M, lda]; B: bf16 row-major [N, ldb] (B^T input).
// 128x128 tile, BK=32, 256 threads = 4 waves (2x2), 4x4 MFMA frags/wave.
// K-loop: depth-1 global_load_lds prefetch, ONE raw s_barrier + s_waitcnt
// vmcnt(4) per iter (tile k+1 loads stay in flight across the barrier).
// Ring-3 safety: slot written at iter k was last read at iter k-2; those reads
// precede barrier(k-1), which precedes iter-k issue. Last iter issues a dummy
// wrap prefetch so the vmcnt count stays uniform.
// mode: 0 = f32 out; 1 = bf16 out; 2 = bf16 out transposed per-(local)batch
//       (dst[b][n][s], b = m>>10, s = m&1023); 3 = f32 accumulate (C += val).
// ---------------------------------------------------------------------------
__global__ __launch_bounds__(256) void gemm_bf16_nt(
    const ushort_t* __restrict__ A, const ushort_t* __restrict__ B,
    const float* __restrict__ bias, void* __restrict__ Cout,
    int K, int lda, int ldb, int ldc, float scale, int mode,
    long long sAz, long long sBz, long long sCz)
{
    A += (long long)blockIdx.z * sAz;
    B += (long long)blockIdx.z * sBz;
    float*    Cf = (float*)Cout    + ((mode == 0 || mode == 3) ? (long long)blockIdx.z * sCz : 0);
    ushort_t* Ch = (ushort_t*)Cout + ((mode == 1 || mode == 2) ? (long long)blockIdx.z * sCz : 0);

    __shared__ ushort_t As[3][128 * 32];   // 3 x 8 KB
    __shared__ ushort_t Bs[3][128 * 32];   // 3 x 8 KB  (48 KB total)

    const int t    = threadIdx.x;       // 0..255
    const int wave = t >> 6;
    const int lane = t & 63;
    const int quad = lane >> 4;         // 0..3
    const int lr   = lane & 15;         // 0..15
    const int wy   = wave >> 1;         // 0/1: m-half
    const int wx   = wave & 1;          // 0/1: n-half

    const int m0 = blockIdx.y * 128;
    const int n0 = blockIdx.x * 128;

    const ushort_t* Abase = A + (long long)m0 * lda;
    const ushort_t* Bbase = B + (long long)n0 * ldb;

    auto issue = [&](int k0, int slot) {
        #pragma unroll
        for (int i = 0; i < 2; ++i) {
            const int idx = t + 256 * i;          // 0..511: 128 rows x 4 chunks
            const int r   = idx >> 2;
            const int c   = (idx & 3) * 8;        // bf16 offset (16B chunks)
            __builtin_amdgcn_global_load_lds(
                (const __attribute__((address_space(1))) unsigned int*)(Abase + (long long)r * lda + k0 + c),
                (__attribute__((address_space(3))) unsigned int*)&As[slot][idx * 8], 16, 0, 0);
            __builtin_amdgcn_global_load_lds(
                (const __attribute__((address_space(1))) unsigned int*)(Bbase + (long long)r * ldb + k0 + c),
                (__attribute__((address_space(3))) unsigned int*)&Bs[slot][idx * 8], 16, 0, 0);
        }
    };

    f32x4 acc[4][4] = {};

    const int NK = K >> 5;
    issue(0, 0);
    int cur = 0, nxt = 1;
    for (int ki = 0; ki < NK; ++ki) {
        const int kn = (ki + 1 < NK) ? (ki + 1) << 5 : 0;  // dummy wrap on last
        issue(kn, nxt);
        asm volatile("s_waitcnt vmcnt(4)" ::: "memory");   // tile-k loads done
        asm volatile("s_barrier" ::: "memory");            // no vmcnt(0) drain

        const ushort_t* as = &As[cur][0];
        const ushort_t* bs = &Bs[cur][0];
        bf16x8 af[4], bfr[4];
        #pragma unroll
        for (int i = 0; i < 4; ++i) {
            const int row = wy * 64 + i * 16 + lr;      // A[m][k]
            af[i] = *(const bf16x8*)&as[row * 32 + quad * 8];
        }
        #pragma unroll
        for (int j = 0; j < 4; ++j) {
            const int row = wx * 64 + j * 16 + lr;      // B^T[n][k]
            bfr[j] = *(const bf16x8*)&bs[row * 32 + quad * 8];
        }
        #pragma unroll
        for (int i = 0; i < 4; ++i)
            #pragma unroll
            for (int j = 0; j < 4; ++j)
                acc[i][j] = __builtin_amdgcn_mfma_f32_16x16x32_bf16(
                    af[i], bfr[j], acc[i][j], 0, 0, 0);

        cur = nxt;
        nxt = (nxt == 2) ? 0 : nxt + 1;
    }

    // epilogue: D row(m) = quad*4 + reg, col(n) = lane&15  [m89-verified]
    #pragma unroll
    for (int j = 0; j < 4; ++j) {
        const int n = n0 + wx * 64 + j * 16 + lr;
        const float bv = bias ? bias[n] : 0.0f;
        #pragma unroll
        for (int i = 0; i < 4; ++i) {
            #pragma unroll
            for (int r = 0; r < 4; ++r) {
                const int m = m0 + wy * 64 + i * 16 + quad * 4 + r;
                const float val = acc[i][j][r] * scale + bv;
                if (mode == 0) {
                    Cf[(long long)m * ldc + n] = val;
                } else if (mode == 3) {
                    Cf[(long long)m * ldc + n] += val;
                } else if (mode == 1) {
                    Ch[(long long)m * ldc + n] = f2bf(val);
                } else {
                    const int b = m >> 10, s = m & 1023;
                    Ch[(long long)b * (DIMV * SEQ) + (long long)n * SEQ + s] = f2bf(val);
                }
            }
        }
    }
}

// ---------------------------------------------------------------------------
// f32 -> bf16 conversion, 4 elems/thread, count divisible by 1024
// ---------------------------------------------------------------------------
__global__ __launch_bounds__(256) void f32_to_bf16(
    const float* __restrict__ in, ushort_t* __restrict__ out)
{
    const long long i = ((long long)blockIdx.x * 256 + threadIdx.x) * 4;
    float4 v = *reinterpret_cast<const float4*>(in + i);
    ushort4 o;
    o.x = f2bf(v.x); o.y = f2bf(v.y); o.z = f2bf(v.z); o.w = f2bf(v.w);
    *reinterpret_cast<ushort4*>(out + i) = o;
}

// ---------------------------------------------------------------------------
// In-place row softmax: 1024 f32 logits -> bf16 probs written over the row
// start (row becomes 1024 bf16 + 2048B dead). All reads complete before the
// first __syncthreads, so the overlapping writes after the last barrier are
// race-free. One 256-thread block per row.
// ---------------------------------------------------------------------------
__global__ __launch_bounds__(256) void softmax_inplace(float* __restrict__ S)
{
    float* s = S + (long long)blockIdx.x * SEQ;
    const int t = threadIdx.x;
    __shared__ float red[256];

    float4 v = *reinterpret_cast<const float4*>(&s[t * 4]);
    float mx = fmaxf(fmaxf(v.x, v.y), fmaxf(v.z, v.w));
    red[t] = mx;
    __syncthreads();
    for (int st = 128; st > 0; st >>= 1) {
        if (t < st) red[t] = fmaxf(red[t], red[t + st]);
        __syncthreads();
    }
    mx = red[0];
    __syncthreads();

    v.x = __expf(v.x - mx); v.y = __expf(v.y - mx);
    v.z = __expf(v.z - mx); v.w = __expf(v.w - mx);
    red[t] = v.x + v.y + v.z + v.w;
    __syncthreads();
    for (int st = 128; st > 0; st >>= 1) {
        if (t < st) red[t] += red[t + st];
        __syncthreads();
    }
    const float inv = 1.0f / red[0];

    ushort4 o;
    o.x = f2bf(v.x * inv); o.y = f2bf(v.y * inv);
    o.z = f2bf(v.z * inv); o.w = f2bf(v.w * inv);
    *reinterpret_cast<ushort4*>((ushort_t*)s + t * 4) = o;
}

// ---------------------------------------------------------------------------
// h = LayerNorm(ACC + xC) * gamma + beta -> bf16. One block per row (768).
// ---------------------------------------------------------------------------
__global__ __launch_bounds__(256) void add_layernorm(
    const float* __restrict__ ACC, const float* __restrict__ xC,
    const float* __restrict__ gamma, const float* __restrict__ beta,
    ushort_t* __restrict__ H)
{
    const long long row = blockIdx.x;
    const float* a = ACC + row * DIMV;
    const float* x = xC  + row * DIMV;
    ushort_t*    h = H   + row * DIMV;
    const int t = threadIdx.x;

    __shared__ float r1[256];
    __shared__ float r2[256];

    float vals[3];
    float s = 0.f, ss = 0.f;
    #pragma unroll
    for (int i = 0; i < 3; ++i) {
        const int j = t + i * 256;
        float v = a[j] + x[j];
        vals[i] = v;
        s += v; ss += v * v;
    }
    r1[t] = s; r2[t] = ss;
    __syncthreads();
    for (int st = 128; st > 0; st >>= 1) {
        if (t < st) { r1[t] += r1[t + st]; r2[t] += r2[t + st]; }
        __syncthreads();
    }
    const float mu  = r1[0] * (1.0f / DIMV);
    const float var = r2[0] * (1.0f / DIMV) - mu * mu;
    const float inv = rsqrtf(var + LN_EPS);

    #pragma unroll
    for (int i = 0; i < 3; ++i) {
        const int j = t + i * 256;
        h[j] = f2bf((vals[i] - mu) * inv * gamma[j] + beta[j]);
    }
}

// ---------------------------------------------------------------------------
// Launch — chunked over batches; footprint adapts to ws_size.
// Persistent: 4 bf16 weight buffers (4.72 MB).
// Per-batch: 6*(S*D)*2 + (S*D)*4 + (S*S)*4 = 16 MB exactly.
// ---------------------------------------------------------------------------
extern "C" void kernel_launch(void* const* d_in, const int* in_sizes, int n_in,
                              void* d_out, int out_size, void* d_ws, size_t ws_size,
                              hipStream_t stream)
{
    const float* xA    = (const float*)d_in[0];
    const float* xB    = (const float*)d_in[1];
    const float* xC    = (const float*)d_in[2];
    const float* Wq    = (const float*)d_in[3];
    const float* bq    = (const float*)d_in[4];
    const float* Wk    = (const float*)d_in[5];
    const float* bk    = (const float*)d_in[6];
    const float* Wv    = (const float*)d_in[7];
    const float* bv    = (const float*)d_in[8];
    const float* gamma = (const float*)d_in[9];
    const float* beta  = (const float*)d_in[10];
    const float* Wfc   = (const float*)d_in[11];
    const float* bfc   = (const float*)d_in[12];
    float* out = (float*)d_out;

    const long long eW   = (long long)DIMV * DIMV;   // 589,824
    const long long perB = (long long)SEQ * DIMV;    // 786,432
    const long long perP = (long long)SEQ * SEQ;     // 1,048,576

    const long long wBytes        = 4 * eW * 2;                  // 4.72 MB
    const long long perBatchBytes = perB * (6 * 2 + 4) + perP * 4; // 16,777,216

    long long Cmax = ((long long)ws_size - wBytes) / perBatchBytes;
    if (Cmax > BATCH) Cmax = BATCH;
    if (Cmax < 1)     Cmax = 1;
    const int nChunks = (int)((BATCH + Cmax - 1) / Cmax);
    const int CbStd   = (BATCH + nChunks - 1) / nChunks;   // balanced chunks

    // persistent weight region
    char* cur = (char*)d_ws;
    ushort_t* Wqb  = (ushort_t*)cur; cur += eW * 2;
    ushort_t* Wkb  = (ushort_t*)cur; cur += eW * 2;
    ushort_t* Wvb  = (ushort_t*)cur; cur += eW * 2;
    ushort_t* Wfcb = (ushort_t*)cur; cur += eW * 2;
    char* chunkBase = cur;

    const float scale = 0.03608439182435161f;  // 1/sqrt(768)

    // 0) convert weights to bf16 (once)
    f32_to_bf16<<<(int)(eW / 1024), 256, 0, stream>>>(Wq,  Wqb);
    f32_to_bf16<<<(int)(eW / 1024), 256, 0, stream>>>(Wk,  Wkb);
    f32_to_bf16<<<(int)(eW / 1024), 256, 0, stream>>>(Wv,  Wvb);
    f32_to_bf16<<<(int)(eW / 1024), 256, 0, stream>>>(Wfc, Wfcb);

    for (int b0 = 0; b0 < BATCH; b0 += CbStd) {
        const int Cb = (b0 + CbStd <= BATCH) ? CbStd : (BATCH - b0);
        const long long off = (long long)b0 * perB;
        const int Mrows = Cb * SEQ;

        // chunk workspace layout
        char* p = chunkBase;
        ushort_t* xb  = (ushort_t*)p; p += (long long)Cb * perB * 2;  // input conv
        ushort_t* Qb  = (ushort_t*)p; p += (long long)Cb * perB * 2;  // Q, later h
        ushort_t* KAb = (ushort_t*)p; p += (long long)Cb * perB * 2;
        ushort_t* KBb = (ushort_t*)p; p += (long long)Cb * perB * 2;
        ushort_t* VtA = (ushort_t*)p; p += (long long)Cb * perB * 2;  // [b][768][1024]
        ushort_t* VtB = (ushort_t*)p; p += (long long)Cb * perB * 2;
        float*    ACC = (float*)p;    p += (long long)Cb * perB * 4;
        float*    Sf  = (float*)p;    p += (long long)Cb * perP * 4;  // logits->probs in-place

        dim3 gproj(DIMV / 128, Mrows / 128, 1);
        dim3 gsc(SEQ / 128, SEQ / 128, Cb);
        dim3 gpv(DIMV / 128, SEQ / 128, Cb);
        const int gcv = (int)((long long)Cb * perB / 1024);

        // 1) projections (shared conversion buffer, stream-serialized)
        f32_to_bf16<<<gcv, 256, 0, stream>>>(xC + off, xb);
        gemm_bf16_nt<<<gproj, 256, 0, stream>>>(xb, Wqb, bq, Qb,  DIMV, DIMV, DIMV, DIMV, 1.f, 1, 0, 0, 0);
        f32_to_bf16<<<gcv, 256, 0, stream>>>(xA + off, xb);
        gemm_bf16_nt<<<gproj, 256, 0, stream>>>(xb, Wkb, bk, KAb, DIMV, DIMV, DIMV, DIMV, 1.f, 1, 0, 0, 0);
        gemm_bf16_nt<<<gproj, 256, 0, stream>>>(xb, Wvb, bv, VtA, DIMV, DIMV, DIMV, DIMV, 1.f, 2, 0, 0, 0);
        f32_to_bf16<<<gcv, 256, 0, stream>>>(xB + off, xb);
        gemm_bf16_nt<<<gproj, 256, 0, stream>>>(xb, Wkb, bk, KBb, DIMV, DIMV, DIMV, DIMV, 1.f, 1, 0, 0, 0);
        gemm_bf16_nt<<<gproj, 256, 0, stream>>>(xb, Wvb, bv, VtB, DIMV, DIMV, DIMV, DIMV, 1.f, 2, 0, 0, 0);

        // 2) branch A: scores -> softmax(in-place) -> PV (write ACC)
        gemm_bf16_nt<<<gsc, 256, 0, stream>>>(Qb, KAb, nullptr, Sf,
            DIMV, DIMV, DIMV, SEQ, scale, 0, perB, perB, perP);
        softmax_inplace<<<Cb * SEQ, 256, 0, stream>>>(Sf);
        gemm_bf16_nt<<<gpv, 256, 0, stream>>>((const ushort_t*)Sf, VtA, nullptr, ACC,
            SEQ, 2 * SEQ, SEQ, DIMV, 1.f, 0, 2 * perP, perB, perB);

        // 3) branch B: scores -> softmax(in-place) -> PV (accumulate into ACC)
        gemm_bf16_nt<<<gsc, 256, 0, stream>>>(Qb, KBb, nullptr, Sf,
            DIMV, DIMV, DIMV, SEQ, scale, 0, perB, perB, perP);
        softmax_inplace<<<Cb * SEQ, 256, 0, stream>>>(Sf);
        gemm_bf16_nt<<<gpv, 256, 0, stream>>>((const ushort_t*)Sf, VtB, nullptr, ACC,
            SEQ, 2 * SEQ, SEQ, DIMV, 1.f, 3, 2 * perP, perB, perB);

        // 4) h = LN(ACC + xC) -> bf16, into Qb (Q is dead now)
        add_layernorm<<<Cb * SEQ, 256, 0, stream>>>(ACC, xC + off, gamma, beta, Qb);

        // 5) out = h @ Wfc^T + bfc (f32 out)
        gemm_bf16_nt<<<gproj, 256, 0, stream>>>(Qb, Wfcb, bfc, out + off,
            DIMV, DIMV, DIMV, DIMV, 1.f, 0, 0, 0, 0);
    }
}